// Round 12
// baseline (365.698 us; speedup 1.0000x reference)
//
#include <hip/hip_runtime.h>

#define NN 50000
#define NE 800000
#define FIN 128
#define FH 256
#define FOUT 40
#define NPAD 50432   // > NN+1, multiple of 64
#define NN2 50048    // NN rounded up to 128
#define NB 256       // dst buckets for the edge sort
#define BSPAN 196    // ceil(NN/NB)
#define EBLK 4096    // edges per binA block
#define NBLK_A 196   // ceil(NE/EBLK)
#define GBLK 1024    // fused gather+colsum grid

typedef float f32x4 __attribute__((ext_vector_type(4)));
typedef short bf16x8 __attribute__((ext_vector_type(8)));

__device__ __forceinline__ ushort f2bf(float f) {
    unsigned u = __float_as_uint(f);
    unsigned r = (u + 0x7FFFu + ((u >> 16) & 1u)) >> 16;   // RNE
    return (ushort)r;
}
__device__ __forceinline__ float bf2f(ushort b) {
    return __uint_as_float(((unsigned)b) << 16);
}

// ---------------- edge sort + CSR build ----------------

__global__ __launch_bounds__(256) void bucket_cnt_kernel(const int* __restrict__ dst,
                                                         int* __restrict__ bcnt) {
    __shared__ int h[NB];
    const int t = threadIdx.x;
    h[t] = 0;
    __syncthreads();
    const int e0 = blockIdx.x * EBLK;
    const int n  = min(EBLK, NE - e0);
    for (int i = t; i < n; i += 256)
        atomicAdd(&h[dst[e0 + i] / BSPAN], 1);
    __syncthreads();
    if (h[t] > 0) atomicAdd(&bcnt[t], h[t]);
}

__global__ __launch_bounds__(256) void bucket_scan_kernel(const int* __restrict__ bcnt,
                                                          int* __restrict__ bbase,
                                                          int* __restrict__ bcur,
                                                          float* __restrict__ vbuf) {
    __shared__ int sh[256];
    int t = threadIdx.x;
    int v = bcnt[t];
    sh[t] = v;
    __syncthreads();
    #pragma unroll
    for (int off = 1; off < 256; off <<= 1) {
        int u = (t >= off) ? sh[t - off] : 0;
        __syncthreads();
        sh[t] += u;
        __syncthreads();
    }
    int excl = sh[t] - v;
    bbase[t] = excl;
    bcur[t]  = excl;
    if (t == 255) bbase[256] = sh[255];   // == NE
    vbuf[t] = 0.0f;
}

__global__ __launch_bounds__(256) void binA_kernel(const int* __restrict__ src,
                                                   const int* __restrict__ dst,
                                                   int* __restrict__ bcur,
                                                   unsigned* __restrict__ inter) {
    __shared__ int hcnt[NB];
    __shared__ int hoff[NB];
    __shared__ int lcur[NB];
    __shared__ int gbase[NB];
    __shared__ unsigned stage[EBLK];   // 16 KB

    const int t  = threadIdx.x;
    const int e0 = blockIdx.x * EBLK;
    const int n  = min(EBLK, NE - e0);

    hcnt[t] = 0;
    __syncthreads();
    for (int i = t; i < n; i += 256)
        atomicAdd(&hcnt[dst[e0 + i] / BSPAN], 1);
    __syncthreads();
    int v = hcnt[t];
    hoff[t] = v;
    __syncthreads();
    #pragma unroll
    for (int off = 1; off < NB; off <<= 1) {
        int u = (t >= off) ? hoff[t - off] : 0;
        __syncthreads();
        hoff[t] += u;
        __syncthreads();
    }
    int excl = hoff[t] - v;
    __syncthreads();
    hoff[t] = excl;
    lcur[t] = excl;
    if (v > 0) gbase[t] = atomicAdd(&bcur[t], v);
    __syncthreads();
    for (int i = t; i < n; i += 256) {
        int d = dst[e0 + i];
        int s = src[e0 + i];
        int b = d / BSPAN;
        int idx = atomicAdd(&lcur[b], 1);
        stage[idx] = ((unsigned)d << 16) | (unsigned)s;   // both < 65536
    }
    __syncthreads();
    for (int i = t; i < n; i += 256) {
        unsigned rec = stage[i];
        int b = (int)(rec >> 16) / BSPAN;
        inter[gbase[b] + (i - hoff[b])] = rec;
    }
}

__global__ __launch_bounds__(256) void binB1_kernel(const unsigned* __restrict__ inter,
                                                    const int* __restrict__ bbase,
                                                    int* __restrict__ row_start,
                                                    float* __restrict__ inv,
                                                    float* __restrict__ wsum) {
    __shared__ int lcnt[BSPAN];
    __shared__ int sh[256];
    const int b   = blockIdx.x;
    const int nlo = b * BSPAN;
    const int nhi = min(nlo + BSPAN, NN);
    const int nn  = nhi - nlo;
    const int base = bbase[b];
    const int cnt  = bbase[b + 1] - base;
    const int t = threadIdx.x;

    for (int i = t; i < nn; i += 256) lcnt[i] = 0;
    __syncthreads();
    for (int i = t; i < cnt; i += 256)
        atomicAdd(&lcnt[(int)(inter[base + i] >> 16) - nlo], 1);
    __syncthreads();
    int c = (t < nn) ? lcnt[t] : 0;
    sh[t] = c;
    __syncthreads();
    #pragma unroll
    for (int off = 1; off < 256; off <<= 1) {
        int u = (t >= off) ? sh[t - off] : 0;
        __syncthreads();
        sh[t] += u;
        __syncthreads();
    }
    if (t < nn) {
        row_start[nlo + t] = base + sh[t] - c;
        inv[nlo + t]  = rsqrtf((float)(c + 1));
        wsum[nlo + t] = 0.0f;
    }
    if (b == NB - 1 && t == 0) row_start[NN] = NE;
}

__global__ __launch_bounds__(256) void binB2_kernel(const unsigned* __restrict__ inter,
                                                    const int* __restrict__ bbase,
                                                    const int* __restrict__ row_start,
                                                    const float* __restrict__ inv,
                                                    float2* __restrict__ edata,
                                                    float* __restrict__ wsum) {
    __shared__ int lcur[BSPAN];
    const int b   = blockIdx.x;
    const int nlo = b * BSPAN;
    const int nhi = min(nlo + BSPAN, NN);
    const int nn  = nhi - nlo;
    const int base = bbase[b];
    const int cnt  = bbase[b + 1] - base;
    const int t = threadIdx.x;

    for (int i = t; i < nn; i += 256) lcur[i] = row_start[nlo + i];
    __syncthreads();
    for (int i = t; i < cnt; i += 256) {
        unsigned rec = inter[base + i];
        int d = (int)(rec >> 16);
        int s = (int)(rec & 0xFFFFu);
        float coef = inv[s] * inv[d];
        int pos = atomicAdd(&lcur[d - nlo], 1);
        edata[pos] = make_float2(__int_as_float(s), coef);
        unsafeAtomicAdd(&wsum[s], coef);
    }
}

// ---------------- prep: W0 split + W1 hi + x -> bf16 (fused, one dispatch) ----------------

__global__ void prep_kernel(const float* __restrict__ W0, const float* __restrict__ W1,
                            const float* __restrict__ x,
                            ushort* __restrict__ W0tH, ushort* __restrict__ W0tL,
                            ushort* __restrict__ W1tH, ushort* __restrict__ xb) {
    int t = blockIdx.x * 256 + threadIdx.x;
    if (t < NN2 * 32) {                       // x conversion, zero-padded rows
        int row = t >> 5;
        int c4  = t & 31;
        ushort4 o = make_ushort4(0, 0, 0, 0);
        if (row < NN) {
            float4 v = *reinterpret_cast<const float4*>(x + (size_t)row * FIN + c4 * 4);
            o = make_ushort4(f2bf(v.x), f2bf(v.y), f2bf(v.z), f2bf(v.w));
        }
        *reinterpret_cast<ushort4*>(xb + (size_t)row * FIN + c4 * 4) = o;
    }
    if (t < FIN * FH) {                       // W0 split+transpose
        int n = t % FH;
        int k = t / FH;
        float f = W0[t];
        ushort h = f2bf(f);
        W0tH[n * FIN + k] = h;
        W0tL[n * FIN + k] = f2bf(f - bf2f(h));
    } else if (t < FIN * FH + FH * FH) {      // W1 hi transpose
        int j = t - FIN * FH;
        int n = j % FH;
        int k = j / FH;
        W1tH[n * FH + k] = f2bf(W1[j]);
    }
}

// ---------------- MFMA GEMM: out_bf16[NN2][256] = A @ Bt^T, 128x256 tile ----------------

template<int TERMS, bool BIAS_RELU>
__global__ __launch_bounds__(256) void gemm_mfma_kernel(
    const ushort* __restrict__ AH, const ushort* __restrict__ AL,
    const ushort* __restrict__ BH, const ushort* __restrict__ BL,
    const float* __restrict__ bias,
    ushort* __restrict__ outB,
    int K) {
    constexpr int NARR = (TERMS == 3) ? 2 : 1;
    __shared__ ushort smem[(128 + 256) * 40 * NARR];
    ushort* Ah = smem;
    ushort* Bh = smem + 128 * 40;
    ushort* Al = (TERMS == 3) ? smem + 384 * 40 : nullptr;
    ushort* Bl = (TERMS == 3) ? smem + 384 * 40 + 128 * 40 : nullptr;

    const int tid  = threadIdx.x;
    const int lane = tid & 63;
    const int w    = tid >> 6;
    const int wr   = w >> 1;
    const int wc   = w & 1;
    const int row0 = blockIdx.x * 128;

    f32x4 acc[4][8] = {};

    for (int k0 = 0; k0 < K; k0 += 32) {
        #pragma unroll
        for (int i = 0; i < 2; ++i) {          // A: 128 rows x 32 k
            int c  = i * 256 + tid;
            int r  = c >> 2;
            int cb = c & 3;
            *reinterpret_cast<uint4*>(&Ah[r * 40 + cb * 8]) =
                *reinterpret_cast<const uint4*>(AH + (size_t)(row0 + r) * K + k0 + cb * 8);
            if (TERMS == 3)
                *reinterpret_cast<uint4*>(&Al[r * 40 + cb * 8]) =
                    *reinterpret_cast<const uint4*>(AL + (size_t)(row0 + r) * K + k0 + cb * 8);
        }
        #pragma unroll
        for (int i = 0; i < 4; ++i) {          // B: 256 rows x 32 k
            int c  = i * 256 + tid;
            int r  = c >> 2;
            int cb = c & 3;
            *reinterpret_cast<uint4*>(&Bh[r * 40 + cb * 8]) =
                *reinterpret_cast<const uint4*>(BH + (size_t)r * K + k0 + cb * 8);
            if (TERMS == 3)
                *reinterpret_cast<uint4*>(&Bl[r * 40 + cb * 8]) =
                    *reinterpret_cast<const uint4*>(BL + (size_t)r * K + k0 + cb * 8);
        }
        __syncthreads();

        const int rsel = lane & 15;
        const int ksel = (lane >> 4) * 8;
        bf16x8 ah[4], bh[8];
        #pragma unroll
        for (int m = 0; m < 4; ++m)
            ah[m] = *reinterpret_cast<const bf16x8*>(&Ah[(wr * 64 + m * 16 + rsel) * 40 + ksel]);
        #pragma unroll
        for (int n = 0; n < 8; ++n)
            bh[n] = *reinterpret_cast<const bf16x8*>(&Bh[(wc * 128 + n * 16 + rsel) * 40 + ksel]);

        if (TERMS == 3) {
            bf16x8 al[4], bl[8];
            #pragma unroll
            for (int m = 0; m < 4; ++m)
                al[m] = *reinterpret_cast<const bf16x8*>(&Al[(wr * 64 + m * 16 + rsel) * 40 + ksel]);
            #pragma unroll
            for (int n = 0; n < 8; ++n)
                bl[n] = *reinterpret_cast<const bf16x8*>(&Bl[(wc * 128 + n * 16 + rsel) * 40 + ksel]);
            #pragma unroll
            for (int m = 0; m < 4; ++m)
                #pragma unroll
                for (int n = 0; n < 8; ++n) {
                    acc[m][n] = __builtin_amdgcn_mfma_f32_16x16x32_bf16(ah[m], bh[n], acc[m][n], 0, 0, 0);
                    acc[m][n] = __builtin_amdgcn_mfma_f32_16x16x32_bf16(ah[m], bl[n], acc[m][n], 0, 0, 0);
                    acc[m][n] = __builtin_amdgcn_mfma_f32_16x16x32_bf16(al[m], bh[n], acc[m][n], 0, 0, 0);
                }
        } else {
            #pragma unroll
            for (int m = 0; m < 4; ++m)
                #pragma unroll
                for (int n = 0; n < 8; ++n)
                    acc[m][n] = __builtin_amdgcn_mfma_f32_16x16x32_bf16(ah[m], bh[n], acc[m][n], 0, 0, 0);
        }
        __syncthreads();
    }

    const int cl = lane & 15;
    const int rg = lane >> 4;
    float bn[8];
    if (BIAS_RELU) {
        #pragma unroll
        for (int n = 0; n < 8; ++n) bn[n] = bias[wc * 128 + n * 16 + cl];
    }
    #pragma unroll
    for (int m = 0; m < 4; ++m) {
        #pragma unroll
        for (int i = 0; i < 4; ++i) {
            int gr = row0 + wr * 64 + m * 16 + rg * 4 + i;
            #pragma unroll
            for (int n = 0; n < 8; ++n) {
                int gc = wc * 128 + n * 16 + cl;
                float o = acc[m][n][i];
                if (BIAS_RELU) o = fmaxf(o + bn[n], 0.0f);
                outB[(size_t)gr * FH + gc] = f2bf(o);
            }
        }
    }
}

// ---------------- gather_x (FIN=128): bf16 in, fp32 acc, split-bf16 out; zero-pads to NN2 ----------------

__global__ __launch_bounds__(256) void gather_x_kernel(const ushort* __restrict__ xb,
                                                       const float2* __restrict__ edata,
                                                       const int* __restrict__ row_start,
                                                       const float* __restrict__ inv,
                                                       ushort* __restrict__ outH,
                                                       ushort* __restrict__ outL) {
    int node = blockIdx.x * 4 + (threadIdx.x >> 6);
    int lane = threadIdx.x & 63;
    if (node >= NN2) return;
    size_t o = (size_t)node * FIN + lane * 2;
    if (node >= NN) {   // zero-pad tail rows for the guard-free GEMM0
        *reinterpret_cast<ushort2*>(outH + o) = make_ushort2(0, 0);
        *reinterpret_cast<ushort2*>(outL + o) = make_ushort2(0, 0);
        return;
    }

    int beg = row_start[node];
    int end = row_start[node + 1];

    float iv = inv[node];
    float c  = iv * iv;
    ushort2 sv = *reinterpret_cast<const ushort2*>(xb + o);
    float2 a0 = make_float2(bf2f(sv.x) * c, bf2f(sv.y) * c);
    float2 a1 = make_float2(0.f, 0.f);
    float2 a2 = make_float2(0.f, 0.f);
    float2 a3 = make_float2(0.f, 0.f);

    int i = beg;
    if ((i & 1) && i < end) {
        float2 ed = edata[i];
        ushort2 u = *reinterpret_cast<const ushort2*>(xb + (size_t)__float_as_int(ed.x) * FIN + lane * 2);
        a0.x += bf2f(u.x) * ed.y; a0.y += bf2f(u.y) * ed.y;
        ++i;
    }
    for (; i + 8 <= end; i += 8) {
        float4 e01 = *reinterpret_cast<const float4*>(&edata[i]);
        float4 e23 = *reinterpret_cast<const float4*>(&edata[i + 2]);
        float4 e45 = *reinterpret_cast<const float4*>(&edata[i + 4]);
        float4 e67 = *reinterpret_cast<const float4*>(&edata[i + 6]);
        ushort2 u0 = *reinterpret_cast<const ushort2*>(xb + (size_t)__float_as_int(e01.x) * FIN + lane * 2);
        ushort2 u1 = *reinterpret_cast<const ushort2*>(xb + (size_t)__float_as_int(e01.z) * FIN + lane * 2);
        ushort2 u2 = *reinterpret_cast<const ushort2*>(xb + (size_t)__float_as_int(e23.x) * FIN + lane * 2);
        ushort2 u3 = *reinterpret_cast<const ushort2*>(xb + (size_t)__float_as_int(e23.z) * FIN + lane * 2);
        ushort2 u4 = *reinterpret_cast<const ushort2*>(xb + (size_t)__float_as_int(e45.x) * FIN + lane * 2);
        ushort2 u5 = *reinterpret_cast<const ushort2*>(xb + (size_t)__float_as_int(e45.z) * FIN + lane * 2);
        ushort2 u6 = *reinterpret_cast<const ushort2*>(xb + (size_t)__float_as_int(e67.x) * FIN + lane * 2);
        ushort2 u7 = *reinterpret_cast<const ushort2*>(xb + (size_t)__float_as_int(e67.z) * FIN + lane * 2);
        a0.x += bf2f(u0.x) * e01.y; a0.y += bf2f(u0.y) * e01.y;
        a1.x += bf2f(u1.x) * e01.w; a1.y += bf2f(u1.y) * e01.w;
        a2.x += bf2f(u2.x) * e23.y; a2.y += bf2f(u2.y) * e23.y;
        a3.x += bf2f(u3.x) * e23.w; a3.y += bf2f(u3.y) * e23.w;
        a0.x += bf2f(u4.x) * e45.y; a0.y += bf2f(u4.y) * e45.y;
        a1.x += bf2f(u5.x) * e45.w; a1.y += bf2f(u5.y) * e45.w;
        a2.x += bf2f(u6.x) * e67.y; a2.y += bf2f(u6.y) * e67.y;
        a3.x += bf2f(u7.x) * e67.w; a3.y += bf2f(u7.y) * e67.w;
    }
    for (; i + 2 <= end; i += 2) {
        float4 e01 = *reinterpret_cast<const float4*>(&edata[i]);
        ushort2 u0 = *reinterpret_cast<const ushort2*>(xb + (size_t)__float_as_int(e01.x) * FIN + lane * 2);
        ushort2 u1 = *reinterpret_cast<const ushort2*>(xb + (size_t)__float_as_int(e01.z) * FIN + lane * 2);
        a0.x += bf2f(u0.x) * e01.y; a0.y += bf2f(u0.y) * e01.y;
        a1.x += bf2f(u1.x) * e01.w; a1.y += bf2f(u1.y) * e01.w;
    }
    if (i < end) {
        float2 ed = edata[i];
        ushort2 u = *reinterpret_cast<const ushort2*>(xb + (size_t)__float_as_int(ed.x) * FIN + lane * 2);
        a0.x += bf2f(u.x) * ed.y; a0.y += bf2f(u.y) * ed.y;
    }

    float ax = a0.x + a1.x + a2.x + a3.x;
    float ay = a0.y + a1.y + a2.y + a3.y;
    ushort h0 = f2bf(ax), h1 = f2bf(ay);
    ushort l0 = f2bf(ax - bf2f(h0)), l1 = f2bf(ay - bf2f(h1));
    *reinterpret_cast<ushort2*>(outH + o) = make_ushort2(h0, h1);
    *reinterpret_cast<ushort2*>(outL + o) = make_ushort2(l0, l1);
}

// ---------------- fused layer-1 gather + collapsed layer-2 colsum ----------------
// For each node: acc = agg(lin1) + b1 (fp32); contribute (wsum+inv^2)*relu(acc) into v.
// No a1 materialization. Grid-stride: 1024 blocks x 4 waves, ~12 nodes/wave; per-block
// LDS reduce then 256 atomics/block (262K atomics total over 256 addrs - negligible).

__global__ __launch_bounds__(256) void gather_colsum_kernel(const ushort* __restrict__ lin,
                                                            const float2* __restrict__ edata,
                                                            const int* __restrict__ row_start,
                                                            const float* __restrict__ inv,
                                                            const float* __restrict__ wsum,
                                                            const float* __restrict__ bias,
                                                            float* __restrict__ v) {
    __shared__ float sh[4][256];
    const int wid  = threadIdx.x >> 6;
    const int lane = threadIdx.x & 63;
    const float4 b = *reinterpret_cast<const float4*>(bias + lane * 4);

    float4 vp = make_float4(0.f, 0.f, 0.f, 0.f);

    for (int node = blockIdx.x * 4 + wid; node < NN; node += GBLK * 4) {
        int beg = row_start[node];
        int end = row_start[node + 1];

        float iv = inv[node];
        float c  = iv * iv;
        ushort4 sv = *reinterpret_cast<const ushort4*>(lin + (size_t)node * FH + lane * 4);
        float4 a0 = make_float4(bf2f(sv.x) * c + b.x, bf2f(sv.y) * c + b.y,
                                bf2f(sv.z) * c + b.z, bf2f(sv.w) * c + b.w);
        float4 a1 = make_float4(0.f, 0.f, 0.f, 0.f);
        float4 a2 = make_float4(0.f, 0.f, 0.f, 0.f);
        float4 a3 = make_float4(0.f, 0.f, 0.f, 0.f);

        int i = beg;
        int pre = (4 - (beg & 3)) & 3;
        int pe = beg + pre; if (pe > end) pe = end;
        for (; i < pe; ++i) {
            float2 ed = edata[i];
            float cf = ed.y;
            ushort4 wv = *reinterpret_cast<const ushort4*>(lin + (size_t)__float_as_int(ed.x) * FH + lane * 4);
            a0.x += bf2f(wv.x) * cf; a0.y += bf2f(wv.y) * cf;
            a0.z += bf2f(wv.z) * cf; a0.w += bf2f(wv.w) * cf;
        }
        for (; i + 4 <= end; i += 4) {
            float4 e01 = *reinterpret_cast<const float4*>(&edata[i]);
            float4 e23 = *reinterpret_cast<const float4*>(&edata[i + 2]);
            ushort4 w0 = *reinterpret_cast<const ushort4*>(lin + (size_t)__float_as_int(e01.x) * FH + lane * 4);
            ushort4 w1 = *reinterpret_cast<const ushort4*>(lin + (size_t)__float_as_int(e01.z) * FH + lane * 4);
            ushort4 w2 = *reinterpret_cast<const ushort4*>(lin + (size_t)__float_as_int(e23.x) * FH + lane * 4);
            ushort4 w3 = *reinterpret_cast<const ushort4*>(lin + (size_t)__float_as_int(e23.z) * FH + lane * 4);
            a0.x += bf2f(w0.x) * e01.y; a0.y += bf2f(w0.y) * e01.y;
            a0.z += bf2f(w0.z) * e01.y; a0.w += bf2f(w0.w) * e01.y;
            a1.x += bf2f(w1.x) * e01.w; a1.y += bf2f(w1.y) * e01.w;
            a1.z += bf2f(w1.z) * e01.w; a1.w += bf2f(w1.w) * e01.w;
            a2.x += bf2f(w2.x) * e23.y; a2.y += bf2f(w2.y) * e23.y;
            a2.z += bf2f(w2.z) * e23.y; a2.w += bf2f(w2.w) * e23.y;
            a3.x += bf2f(w3.x) * e23.w; a3.y += bf2f(w3.y) * e23.w;
            a3.z += bf2f(w3.z) * e23.w; a3.w += bf2f(w3.w) * e23.w;
        }
        for (; i < end; ++i) {
            float2 ed = edata[i];
            float cf = ed.y;
            ushort4 wv = *reinterpret_cast<const ushort4*>(lin + (size_t)__float_as_int(ed.x) * FH + lane * 4);
            a0.x += bf2f(wv.x) * cf; a0.y += bf2f(wv.y) * cf;
            a0.z += bf2f(wv.z) * cf; a0.w += bf2f(wv.w) * cf;
        }

        float wn = wsum[node] + c;
        vp.x += fmaxf(a0.x + a1.x + a2.x + a3.x, 0.f) * wn;
        vp.y += fmaxf(a0.y + a1.y + a2.y + a3.y, 0.f) * wn;
        vp.z += fmaxf(a0.z + a1.z + a2.z + a3.z, 0.f) * wn;
        vp.w += fmaxf(a0.w + a1.w + a2.w + a3.w, 0.f) * wn;
    }

    *reinterpret_cast<float4*>(&sh[wid][lane * 4]) = vp;
    __syncthreads();
    if (wid == 0) {
        float4 s1 = *reinterpret_cast<const float4*>(&sh[1][lane * 4]);
        float4 s2 = *reinterpret_cast<const float4*>(&sh[2][lane * 4]);
        float4 s3 = *reinterpret_cast<const float4*>(&sh[3][lane * 4]);
        unsafeAtomicAdd(&v[lane * 4 + 0], vp.x + s1.x + s2.x + s3.x);
        unsafeAtomicAdd(&v[lane * 4 + 1], vp.y + s1.y + s2.y + s3.y);
        unsafeAtomicAdd(&v[lane * 4 + 2], vp.z + s1.z + s2.z + s3.z);
        unsafeAtomicAdd(&v[lane * 4 + 3], vp.w + s1.w + s2.w + s3.w);
    }
}

// out = ((v/NN) @ W2 + b2) @ Wh + bh
__global__ __launch_bounds__(256) void head2_kernel(const float* __restrict__ v,
                                                    const float* __restrict__ W2,
                                                    const float* __restrict__ b2,
                                                    const float* __restrict__ Wh,
                                                    const float* __restrict__ bh,
                                                    float* __restrict__ out) {
    __shared__ float m[FH];
    int t = threadIdx.x;
    const float scale = 1.0f / (float)NN;
    float s = 0.0f;
    for (int f = 0; f < FH; ++f)
        s += v[f] * W2[f * FH + t];
    m[t] = s * scale + b2[t];
    __syncthreads();
    if (t < FOUT) {
        float o = 0.0f;
        for (int f = 0; f < FH; ++f)
            o += m[f] * Wh[f * FOUT + t];
        out[t] = o + bh[t];
    }
}

// ---------------- launch ----------------

extern "C" void kernel_launch(void* const* d_in, const int* in_sizes, int n_in,
                              void* d_out, int out_size, void* d_ws, size_t ws_size,
                              hipStream_t stream) {
    const float* x   = (const float*)d_in[0];
    const int*   ei  = (const int*)d_in[1];
    const float* W0  = (const float*)d_in[2];
    const float* b0  = (const float*)d_in[3];
    const float* W1  = (const float*)d_in[4];
    const float* b1  = (const float*)d_in[5];
    const float* W2  = (const float*)d_in[6];
    const float* b2  = (const float*)d_in[7];
    const float* Wh  = (const float*)d_in[8];
    const float* bh  = (const float*)d_in[9];
    float* out = (float*)d_out;

    const int* src = ei;        // edge_index[0,:]
    const int* dst = ei + NE;   // edge_index[1,:]

    // workspace layout (16B-aligned blocks)
    float*    inv       = (float*)d_ws;                 // NPAD
    int*      row_start = (int*)(inv + NPAD);           // NPAD (NN+1 used)
    float*    wsum      = (float*)(row_start + NPAD);   // NPAD
    int*      bcnt      = (int*)(wsum + NPAD);          // 256
    int*      bbase     = bcnt + 256;                   // 320 (257 used)
    int*      bcur      = bbase + 320;                  // 256
    float*    vbuf      = (float*)(bcur + 256);         // 256
    unsigned* inter     = (unsigned*)(vbuf + 256);      // NE u32 (3.2 MB)
    float2*   edata     = (float2*)(inter + NE);        // NE float2 (6.4 MB)
    ushort*   W0tH      = (ushort*)(edata + NE);        // [256][128]
    ushort*   W0tL      = W0tH + 256 * 128;
    ushort*   W1tH      = W0tL + 256 * 128;             // [256][256]
    ushort*   xb        = W1tH + 256 * 256;             // [NN2][128] bf16 (12.8 MB)
    ushort*   aggxH     = xb + (size_t)NN2 * 128;       // [NN2][128]
    ushort*   aggxL     = aggxH + (size_t)NN2 * 128;
    ushort*   linb      = aggxH;                        // [NN2][256] bf16 (aggx dead)
    ushort*   h0H       = aggxL + (size_t)NN2 * 128;    // [NN2][256]

    const int gemm_grid = NN2 / 128;                    // 391
    const int nblk_gx = NN2 / 4;

    // ---- edge sort + CSR build + prep ----
    hipMemsetAsync(bcnt, 0, NB * sizeof(int), stream);
    bucket_cnt_kernel<<<NBLK_A, 256, 0, stream>>>(dst, bcnt);
    bucket_scan_kernel<<<1, 256, 0, stream>>>(bcnt, bbase, bcur, vbuf);
    binA_kernel<<<NBLK_A, 256, 0, stream>>>(src, dst, bcur, inter);
    binB1_kernel<<<NB, 256, 0, stream>>>(inter, bbase, row_start, inv, wsum);
    binB2_kernel<<<NB, 256, 0, stream>>>(inter, bbase, row_start, inv, edata, wsum);
    prep_kernel<<<(NN2 * 32 + 255) / 256, 256, 0, stream>>>(W0, W1, x, W0tH, W0tL, W1tH, xb);

    // layer 0: aggx = agg(xb) [split]; h0 = bf16(relu(aggx @ W0 + b0))   (3-term)
    gather_x_kernel<<<nblk_gx, 256, 0, stream>>>(xb, edata, row_start, inv, aggxH, aggxL);
    gemm_mfma_kernel<3, true><<<gemm_grid, 256, 0, stream>>>(aggxH, aggxL, W0tH, W0tL, b0,
                                                             h0H, FIN);

    // layer 1 GEMM: lin1 = bf16(h0 @ W1)
    gemm_mfma_kernel<1, false><<<gemm_grid, 256, 0, stream>>>(h0H, nullptr, W1tH, nullptr, nullptr,
                                                              linb, FH);

    // fused: layer-1 gather + relu + collapsed layer-2 weighted colsum -> vbuf
    gather_colsum_kernel<<<GBLK, 256, 0, stream>>>(linb, edata, row_start, inv, wsum, b1, vbuf);

    // head
    head2_kernel<<<1, 256, 0, stream>>>(vbuf, W2, b2, Wh, bh, out);
}

// Round 13
// 282.785 us; speedup vs baseline: 1.2932x; 1.2932x over previous
//
#include <hip/hip_runtime.h>

#define NN 50000
#define NE 800000
#define FIN 128
#define FH 256
#define FOUT 40
#define NPAD 50432   // > NN+1, multiple of 64
#define NN2 50048    // NN rounded up to 128
#define NB 256       // dst buckets for the edge sort
#define BSPAN 196    // ceil(NN/NB)
#define EBLK 4096    // edges per binA block
#define NBLK_A 196   // ceil(NE/EBLK)
#define NVP 64       // vpart copies (atomic spread)

typedef float f32x4 __attribute__((ext_vector_type(4)));
typedef short bf16x8 __attribute__((ext_vector_type(8)));

__device__ __forceinline__ ushort f2bf(float f) {
    unsigned u = __float_as_uint(f);
    unsigned r = (u + 0x7FFFu + ((u >> 16) & 1u)) >> 16;   // RNE
    return (ushort)r;
}
__device__ __forceinline__ float bf2f(ushort b) {
    return __uint_as_float(((unsigned)b) << 16);
}

// ---------------- edge sort + CSR build ----------------

__global__ __launch_bounds__(256) void bucket_cnt_kernel(const int* __restrict__ dst,
                                                         int* __restrict__ bcnt) {
    __shared__ int h[NB];
    const int t = threadIdx.x;
    h[t] = 0;
    __syncthreads();
    const int e0 = blockIdx.x * EBLK;
    const int n  = min(EBLK, NE - e0);
    for (int i = t; i < n; i += 256)
        atomicAdd(&h[dst[e0 + i] / BSPAN], 1);
    __syncthreads();
    if (h[t] > 0) atomicAdd(&bcnt[t], h[t]);
}

__global__ __launch_bounds__(256) void bucket_scan_kernel(const int* __restrict__ bcnt,
                                                          int* __restrict__ bbase,
                                                          int* __restrict__ bcur) {
    __shared__ int sh[256];
    int t = threadIdx.x;
    int v = bcnt[t];
    sh[t] = v;
    __syncthreads();
    #pragma unroll
    for (int off = 1; off < 256; off <<= 1) {
        int u = (t >= off) ? sh[t - off] : 0;
        __syncthreads();
        sh[t] += u;
        __syncthreads();
    }
    int excl = sh[t] - v;
    bbase[t] = excl;
    bcur[t]  = excl;
    if (t == 255) bbase[256] = sh[255];   // == NE
}

__global__ __launch_bounds__(256) void binA_kernel(const int* __restrict__ src,
                                                   const int* __restrict__ dst,
                                                   int* __restrict__ bcur,
                                                   unsigned* __restrict__ inter) {
    __shared__ int hcnt[NB];
    __shared__ int hoff[NB];
    __shared__ int lcur[NB];
    __shared__ int gbase[NB];
    __shared__ unsigned stage[EBLK];   // 16 KB

    const int t  = threadIdx.x;
    const int e0 = blockIdx.x * EBLK;
    const int n  = min(EBLK, NE - e0);

    hcnt[t] = 0;
    __syncthreads();
    for (int i = t; i < n; i += 256)
        atomicAdd(&hcnt[dst[e0 + i] / BSPAN], 1);
    __syncthreads();
    int v = hcnt[t];
    hoff[t] = v;
    __syncthreads();
    #pragma unroll
    for (int off = 1; off < NB; off <<= 1) {
        int u = (t >= off) ? hoff[t - off] : 0;
        __syncthreads();
        hoff[t] += u;
        __syncthreads();
    }
    int excl = hoff[t] - v;
    __syncthreads();
    hoff[t] = excl;
    lcur[t] = excl;
    if (v > 0) gbase[t] = atomicAdd(&bcur[t], v);
    __syncthreads();
    for (int i = t; i < n; i += 256) {
        int d = dst[e0 + i];
        int s = src[e0 + i];
        int b = d / BSPAN;
        int idx = atomicAdd(&lcur[b], 1);
        stage[idx] = ((unsigned)d << 16) | (unsigned)s;   // both < 65536
    }
    __syncthreads();
    for (int i = t; i < n; i += 256) {
        unsigned rec = stage[i];
        int b = (int)(rec >> 16) / BSPAN;
        inter[gbase[b] + (i - hoff[b])] = rec;
    }
}

__global__ __launch_bounds__(256) void binB1_kernel(const unsigned* __restrict__ inter,
                                                    const int* __restrict__ bbase,
                                                    int* __restrict__ row_start,
                                                    float* __restrict__ inv,
                                                    float* __restrict__ wsum) {
    __shared__ int lcnt[BSPAN];
    __shared__ int sh[256];
    const int b   = blockIdx.x;
    const int nlo = b * BSPAN;
    const int nhi = min(nlo + BSPAN, NN);
    const int nn  = nhi - nlo;
    const int base = bbase[b];
    const int cnt  = bbase[b + 1] - base;
    const int t = threadIdx.x;

    for (int i = t; i < nn; i += 256) lcnt[i] = 0;
    __syncthreads();
    for (int i = t; i < cnt; i += 256)
        atomicAdd(&lcnt[(int)(inter[base + i] >> 16) - nlo], 1);
    __syncthreads();
    int c = (t < nn) ? lcnt[t] : 0;
    sh[t] = c;
    __syncthreads();
    #pragma unroll
    for (int off = 1; off < 256; off <<= 1) {
        int u = (t >= off) ? sh[t - off] : 0;
        __syncthreads();
        sh[t] += u;
        __syncthreads();
    }
    if (t < nn) {
        row_start[nlo + t] = base + sh[t] - c;
        inv[nlo + t]  = rsqrtf((float)(c + 1));
        wsum[nlo + t] = 0.0f;
    }
    if (b == NB - 1 && t == 0) row_start[NN] = NE;
}

__global__ __launch_bounds__(256) void binB2_kernel(const unsigned* __restrict__ inter,
                                                    const int* __restrict__ bbase,
                                                    const int* __restrict__ row_start,
                                                    const float* __restrict__ inv,
                                                    float2* __restrict__ edata,
                                                    float* __restrict__ wsum) {
    __shared__ int lcur[BSPAN];
    const int b   = blockIdx.x;
    const int nlo = b * BSPAN;
    const int nhi = min(nlo + BSPAN, NN);
    const int nn  = nhi - nlo;
    const int base = bbase[b];
    const int cnt  = bbase[b + 1] - base;
    const int t = threadIdx.x;

    for (int i = t; i < nn; i += 256) lcur[i] = row_start[nlo + i];
    __syncthreads();
    for (int i = t; i < cnt; i += 256) {
        unsigned rec = inter[base + i];
        int d = (int)(rec >> 16);
        int s = (int)(rec & 0xFFFFu);
        float coef = inv[s] * inv[d];
        int pos = atomicAdd(&lcur[d - nlo], 1);
        edata[pos] = make_float2(__int_as_float(s), coef);
        unsafeAtomicAdd(&wsum[s], coef);
    }
}

// ---------------- prep: W0 split + W1 hi + x -> bf16 (fused, one dispatch) ----------------

__global__ void prep_kernel(const float* __restrict__ W0, const float* __restrict__ W1,
                            const float* __restrict__ x,
                            ushort* __restrict__ W0tH, ushort* __restrict__ W0tL,
                            ushort* __restrict__ W1tH, ushort* __restrict__ xb) {
    int t = blockIdx.x * 256 + threadIdx.x;
    if (t < NN2 * 32) {                       // x conversion, zero-padded rows
        int row = t >> 5;
        int c4  = t & 31;
        ushort4 o = make_ushort4(0, 0, 0, 0);
        if (row < NN) {
            float4 v = *reinterpret_cast<const float4*>(x + (size_t)row * FIN + c4 * 4);
            o = make_ushort4(f2bf(v.x), f2bf(v.y), f2bf(v.z), f2bf(v.w));
        }
        *reinterpret_cast<ushort4*>(xb + (size_t)row * FIN + c4 * 4) = o;
    }
    if (t < FIN * FH) {                       // W0 split+transpose
        int n = t % FH;
        int k = t / FH;
        float f = W0[t];
        ushort h = f2bf(f);
        W0tH[n * FIN + k] = h;
        W0tL[n * FIN + k] = f2bf(f - bf2f(h));
    } else if (t < FIN * FH + FH * FH) {      // W1 hi transpose
        int j = t - FIN * FH;
        int n = j % FH;
        int k = j / FH;
        W1tH[n * FH + k] = f2bf(W1[j]);
    }
}

// ---------------- MFMA GEMM: out_bf16[NN2][256] = A @ Bt^T, 128x256 tile ----------------

template<int TERMS, bool BIAS_RELU>
__global__ __launch_bounds__(256) void gemm_mfma_kernel(
    const ushort* __restrict__ AH, const ushort* __restrict__ AL,
    const ushort* __restrict__ BH, const ushort* __restrict__ BL,
    const float* __restrict__ bias,
    ushort* __restrict__ outB,
    int K) {
    constexpr int NARR = (TERMS == 3) ? 2 : 1;
    __shared__ ushort smem[(128 + 256) * 40 * NARR];
    ushort* Ah = smem;
    ushort* Bh = smem + 128 * 40;
    ushort* Al = (TERMS == 3) ? smem + 384 * 40 : nullptr;
    ushort* Bl = (TERMS == 3) ? smem + 384 * 40 + 128 * 40 : nullptr;

    const int tid  = threadIdx.x;
    const int lane = tid & 63;
    const int w    = tid >> 6;
    const int wr   = w >> 1;
    const int wc   = w & 1;
    const int row0 = blockIdx.x * 128;

    f32x4 acc[4][8] = {};

    for (int k0 = 0; k0 < K; k0 += 32) {
        #pragma unroll
        for (int i = 0; i < 2; ++i) {          // A: 128 rows x 32 k
            int c  = i * 256 + tid;
            int r  = c >> 2;
            int cb = c & 3;
            *reinterpret_cast<uint4*>(&Ah[r * 40 + cb * 8]) =
                *reinterpret_cast<const uint4*>(AH + (size_t)(row0 + r) * K + k0 + cb * 8);
            if (TERMS == 3)
                *reinterpret_cast<uint4*>(&Al[r * 40 + cb * 8]) =
                    *reinterpret_cast<const uint4*>(AL + (size_t)(row0 + r) * K + k0 + cb * 8);
        }
        #pragma unroll
        for (int i = 0; i < 4; ++i) {          // B: 256 rows x 32 k
            int c  = i * 256 + tid;
            int r  = c >> 2;
            int cb = c & 3;
            *reinterpret_cast<uint4*>(&Bh[r * 40 + cb * 8]) =
                *reinterpret_cast<const uint4*>(BH + (size_t)r * K + k0 + cb * 8);
            if (TERMS == 3)
                *reinterpret_cast<uint4*>(&Bl[r * 40 + cb * 8]) =
                    *reinterpret_cast<const uint4*>(BL + (size_t)r * K + k0 + cb * 8);
        }
        __syncthreads();

        const int rsel = lane & 15;
        const int ksel = (lane >> 4) * 8;
        bf16x8 ah[4], bh[8];
        #pragma unroll
        for (int m = 0; m < 4; ++m)
            ah[m] = *reinterpret_cast<const bf16x8*>(&Ah[(wr * 64 + m * 16 + rsel) * 40 + ksel]);
        #pragma unroll
        for (int n = 0; n < 8; ++n)
            bh[n] = *reinterpret_cast<const bf16x8*>(&Bh[(wc * 128 + n * 16 + rsel) * 40 + ksel]);

        if (TERMS == 3) {
            bf16x8 al[4], bl[8];
            #pragma unroll
            for (int m = 0; m < 4; ++m)
                al[m] = *reinterpret_cast<const bf16x8*>(&Al[(wr * 64 + m * 16 + rsel) * 40 + ksel]);
            #pragma unroll
            for (int n = 0; n < 8; ++n)
                bl[n] = *reinterpret_cast<const bf16x8*>(&Bl[(wc * 128 + n * 16 + rsel) * 40 + ksel]);
            #pragma unroll
            for (int m = 0; m < 4; ++m)
                #pragma unroll
                for (int n = 0; n < 8; ++n) {
                    acc[m][n] = __builtin_amdgcn_mfma_f32_16x16x32_bf16(ah[m], bh[n], acc[m][n], 0, 0, 0);
                    acc[m][n] = __builtin_amdgcn_mfma_f32_16x16x32_bf16(ah[m], bl[n], acc[m][n], 0, 0, 0);
                    acc[m][n] = __builtin_amdgcn_mfma_f32_16x16x32_bf16(al[m], bh[n], acc[m][n], 0, 0, 0);
                }
        } else {
            #pragma unroll
            for (int m = 0; m < 4; ++m)
                #pragma unroll
                for (int n = 0; n < 8; ++n)
                    acc[m][n] = __builtin_amdgcn_mfma_f32_16x16x32_bf16(ah[m], bh[n], acc[m][n], 0, 0, 0);
        }
        __syncthreads();
    }

    const int cl = lane & 15;
    const int rg = lane >> 4;
    float bn[8];
    if (BIAS_RELU) {
        #pragma unroll
        for (int n = 0; n < 8; ++n) bn[n] = bias[wc * 128 + n * 16 + cl];
    }
    #pragma unroll
    for (int m = 0; m < 4; ++m) {
        #pragma unroll
        for (int i = 0; i < 4; ++i) {
            int gr = row0 + wr * 64 + m * 16 + rg * 4 + i;
            #pragma unroll
            for (int n = 0; n < 8; ++n) {
                int gc = wc * 128 + n * 16 + cl;
                float o = acc[m][n][i];
                if (BIAS_RELU) o = fmaxf(o + bn[n], 0.0f);
                outB[(size_t)gr * FH + gc] = f2bf(o);
            }
        }
    }
}

// ---------------- gather_x (FIN=128): bf16 in, fp32 acc, split-bf16 out; zero-pads to NN2 ----------------

__global__ __launch_bounds__(256) void gather_x_kernel(const ushort* __restrict__ xb,
                                                       const float2* __restrict__ edata,
                                                       const int* __restrict__ row_start,
                                                       const float* __restrict__ inv,
                                                       ushort* __restrict__ outH,
                                                       ushort* __restrict__ outL) {
    int node = blockIdx.x * 4 + (threadIdx.x >> 6);
    int lane = threadIdx.x & 63;
    if (node >= NN2) return;
    size_t o = (size_t)node * FIN + lane * 2;
    if (node >= NN) {   // zero-pad tail rows for the guard-free GEMM0
        *reinterpret_cast<ushort2*>(outH + o) = make_ushort2(0, 0);
        *reinterpret_cast<ushort2*>(outL + o) = make_ushort2(0, 0);
        return;
    }

    int beg = row_start[node];
    int end = row_start[node + 1];

    float iv = inv[node];
    float c  = iv * iv;
    ushort2 sv = *reinterpret_cast<const ushort2*>(xb + o);
    float2 a0 = make_float2(bf2f(sv.x) * c, bf2f(sv.y) * c);
    float2 a1 = make_float2(0.f, 0.f);
    float2 a2 = make_float2(0.f, 0.f);
    float2 a3 = make_float2(0.f, 0.f);

    int i = beg;
    if ((i & 1) && i < end) {
        float2 ed = edata[i];
        ushort2 u = *reinterpret_cast<const ushort2*>(xb + (size_t)__float_as_int(ed.x) * FIN + lane * 2);
        a0.x += bf2f(u.x) * ed.y; a0.y += bf2f(u.y) * ed.y;
        ++i;
    }
    for (; i + 8 <= end; i += 8) {
        float4 e01 = *reinterpret_cast<const float4*>(&edata[i]);
        float4 e23 = *reinterpret_cast<const float4*>(&edata[i + 2]);
        float4 e45 = *reinterpret_cast<const float4*>(&edata[i + 4]);
        float4 e67 = *reinterpret_cast<const float4*>(&edata[i + 6]);
        ushort2 u0 = *reinterpret_cast<const ushort2*>(xb + (size_t)__float_as_int(e01.x) * FIN + lane * 2);
        ushort2 u1 = *reinterpret_cast<const ushort2*>(xb + (size_t)__float_as_int(e01.z) * FIN + lane * 2);
        ushort2 u2 = *reinterpret_cast<const ushort2*>(xb + (size_t)__float_as_int(e23.x) * FIN + lane * 2);
        ushort2 u3 = *reinterpret_cast<const ushort2*>(xb + (size_t)__float_as_int(e23.z) * FIN + lane * 2);
        ushort2 u4 = *reinterpret_cast<const ushort2*>(xb + (size_t)__float_as_int(e45.x) * FIN + lane * 2);
        ushort2 u5 = *reinterpret_cast<const ushort2*>(xb + (size_t)__float_as_int(e45.z) * FIN + lane * 2);
        ushort2 u6 = *reinterpret_cast<const ushort2*>(xb + (size_t)__float_as_int(e67.x) * FIN + lane * 2);
        ushort2 u7 = *reinterpret_cast<const ushort2*>(xb + (size_t)__float_as_int(e67.z) * FIN + lane * 2);
        a0.x += bf2f(u0.x) * e01.y; a0.y += bf2f(u0.y) * e01.y;
        a1.x += bf2f(u1.x) * e01.w; a1.y += bf2f(u1.y) * e01.w;
        a2.x += bf2f(u2.x) * e23.y; a2.y += bf2f(u2.y) * e23.y;
        a3.x += bf2f(u3.x) * e23.w; a3.y += bf2f(u3.y) * e23.w;
        a0.x += bf2f(u4.x) * e45.y; a0.y += bf2f(u4.y) * e45.y;
        a1.x += bf2f(u5.x) * e45.w; a1.y += bf2f(u5.y) * e45.w;
        a2.x += bf2f(u6.x) * e67.y; a2.y += bf2f(u6.y) * e67.y;
        a3.x += bf2f(u7.x) * e67.w; a3.y += bf2f(u7.y) * e67.w;
    }
    for (; i + 2 <= end; i += 2) {
        float4 e01 = *reinterpret_cast<const float4*>(&edata[i]);
        ushort2 u0 = *reinterpret_cast<const ushort2*>(xb + (size_t)__float_as_int(e01.x) * FIN + lane * 2);
        ushort2 u1 = *reinterpret_cast<const ushort2*>(xb + (size_t)__float_as_int(e01.z) * FIN + lane * 2);
        a0.x += bf2f(u0.x) * e01.y; a0.y += bf2f(u0.y) * e01.y;
        a1.x += bf2f(u1.x) * e01.w; a1.y += bf2f(u1.y) * e01.w;
    }
    if (i < end) {
        float2 ed = edata[i];
        ushort2 u = *reinterpret_cast<const ushort2*>(xb + (size_t)__float_as_int(ed.x) * FIN + lane * 2);
        a0.x += bf2f(u.x) * ed.y; a0.y += bf2f(u.y) * ed.y;
    }

    float ax = a0.x + a1.x + a2.x + a3.x;
    float ay = a0.y + a1.y + a2.y + a3.y;
    ushort h0 = f2bf(ax), h1 = f2bf(ay);
    ushort l0 = f2bf(ax - bf2f(h0)), l1 = f2bf(ay - bf2f(h1));
    *reinterpret_cast<ushort2*>(outH + o) = make_ushort2(h0, h1);
    *reinterpret_cast<ushort2*>(outL + o) = make_ushort2(l0, l1);
}

// ---------------- fused layer-1 gather + collapsed layer-2 colsum (FULL parallelism) ----------------
// One node per wave (50000 waves, NN = 12500*4 exactly -> no guards). Per node:
// acc = agg(lin1)+b1 (fp32, x8 MLP); vp += (wsum+inv^2)*relu(acc). Block LDS-reduce,
// then 256 atomics into vpart[blockIdx & 63] (64 copies -> ~195 hits/address).

__global__ __launch_bounds__(256) void gather_colsum_kernel(const ushort* __restrict__ lin,
                                                            const float2* __restrict__ edata,
                                                            const int* __restrict__ row_start,
                                                            const float* __restrict__ inv,
                                                            const float* __restrict__ wsum,
                                                            const float* __restrict__ bias,
                                                            float* __restrict__ vpart) {
    __shared__ float sh[4][256];
    const int wid  = threadIdx.x >> 6;
    const int lane = threadIdx.x & 63;
    const int node = blockIdx.x * 4 + wid;     // always < NN (12500*4 == NN)

    int beg = row_start[node];
    int end = row_start[node + 1];

    float iv = inv[node];
    float c  = iv * iv;
    ushort4 sv = *reinterpret_cast<const ushort4*>(lin + (size_t)node * FH + lane * 4);
    float4 b = *reinterpret_cast<const float4*>(bias + lane * 4);
    float4 a0 = make_float4(bf2f(sv.x) * c + b.x, bf2f(sv.y) * c + b.y,
                            bf2f(sv.z) * c + b.z, bf2f(sv.w) * c + b.w);
    float4 a1 = make_float4(0.f, 0.f, 0.f, 0.f);
    float4 a2 = make_float4(0.f, 0.f, 0.f, 0.f);
    float4 a3 = make_float4(0.f, 0.f, 0.f, 0.f);

    int i = beg;
    if ((i & 1) && i < end) {
        float2 ed = edata[i];
        float cf = ed.y;
        ushort4 wv = *reinterpret_cast<const ushort4*>(lin + (size_t)__float_as_int(ed.x) * FH + lane * 4);
        a0.x += bf2f(wv.x) * cf; a0.y += bf2f(wv.y) * cf;
        a0.z += bf2f(wv.z) * cf; a0.w += bf2f(wv.w) * cf;
        ++i;
    }
    for (; i + 8 <= end; i += 8) {
        float4 e01 = *reinterpret_cast<const float4*>(&edata[i]);
        float4 e23 = *reinterpret_cast<const float4*>(&edata[i + 2]);
        float4 e45 = *reinterpret_cast<const float4*>(&edata[i + 4]);
        float4 e67 = *reinterpret_cast<const float4*>(&edata[i + 6]);
        ushort4 w0 = *reinterpret_cast<const ushort4*>(lin + (size_t)__float_as_int(e01.x) * FH + lane * 4);
        ushort4 w1 = *reinterpret_cast<const ushort4*>(lin + (size_t)__float_as_int(e01.z) * FH + lane * 4);
        ushort4 w2 = *reinterpret_cast<const ushort4*>(lin + (size_t)__float_as_int(e23.x) * FH + lane * 4);
        ushort4 w3 = *reinterpret_cast<const ushort4*>(lin + (size_t)__float_as_int(e23.z) * FH + lane * 4);
        ushort4 w4 = *reinterpret_cast<const ushort4*>(lin + (size_t)__float_as_int(e45.x) * FH + lane * 4);
        ushort4 w5 = *reinterpret_cast<const ushort4*>(lin + (size_t)__float_as_int(e45.z) * FH + lane * 4);
        ushort4 w6 = *reinterpret_cast<const ushort4*>(lin + (size_t)__float_as_int(e67.x) * FH + lane * 4);
        ushort4 w7 = *reinterpret_cast<const ushort4*>(lin + (size_t)__float_as_int(e67.z) * FH + lane * 4);
        a0.x += bf2f(w0.x) * e01.y; a0.y += bf2f(w0.y) * e01.y;
        a0.z += bf2f(w0.z) * e01.y; a0.w += bf2f(w0.w) * e01.y;
        a1.x += bf2f(w1.x) * e01.w; a1.y += bf2f(w1.y) * e01.w;
        a1.z += bf2f(w1.z) * e01.w; a1.w += bf2f(w1.w) * e01.w;
        a2.x += bf2f(w2.x) * e23.y; a2.y += bf2f(w2.y) * e23.y;
        a2.z += bf2f(w2.z) * e23.y; a2.w += bf2f(w2.w) * e23.y;
        a3.x += bf2f(w3.x) * e23.w; a3.y += bf2f(w3.y) * e23.w;
        a3.z += bf2f(w3.z) * e23.w; a3.w += bf2f(w3.w) * e23.w;
        a0.x += bf2f(w4.x) * e45.y; a0.y += bf2f(w4.y) * e45.y;
        a0.z += bf2f(w4.z) * e45.y; a0.w += bf2f(w4.w) * e45.y;
        a1.x += bf2f(w5.x) * e45.w; a1.y += bf2f(w5.y) * e45.w;
        a1.z += bf2f(w5.z) * e45.w; a1.w += bf2f(w5.w) * e45.w;
        a2.x += bf2f(w6.x) * e67.y; a2.y += bf2f(w6.y) * e67.y;
        a2.z += bf2f(w6.z) * e67.y; a2.w += bf2f(w6.w) * e67.y;
        a3.x += bf2f(w7.x) * e67.w; a3.y += bf2f(w7.y) * e67.w;
        a3.z += bf2f(w7.z) * e67.w; a3.w += bf2f(w7.w) * e67.w;
    }
    for (; i + 2 <= end; i += 2) {
        float4 e01 = *reinterpret_cast<const float4*>(&edata[i]);
        ushort4 w0 = *reinterpret_cast<const ushort4*>(lin + (size_t)__float_as_int(e01.x) * FH + lane * 4);
        ushort4 w1 = *reinterpret_cast<const ushort4*>(lin + (size_t)__float_as_int(e01.z) * FH + lane * 4);
        a0.x += bf2f(w0.x) * e01.y; a0.y += bf2f(w0.y) * e01.y;
        a0.z += bf2f(w0.z) * e01.y; a0.w += bf2f(w0.w) * e01.y;
        a1.x += bf2f(w1.x) * e01.w; a1.y += bf2f(w1.y) * e01.w;
        a1.z += bf2f(w1.z) * e01.w; a1.w += bf2f(w1.w) * e01.w;
    }
    if (i < end) {
        float2 ed = edata[i];
        float cf = ed.y;
        ushort4 wv = *reinterpret_cast<const ushort4*>(lin + (size_t)__float_as_int(ed.x) * FH + lane * 4);
        a0.x += bf2f(wv.x) * cf; a0.y += bf2f(wv.y) * cf;
        a0.z += bf2f(wv.z) * cf; a0.w += bf2f(wv.w) * cf;
    }

    float wn = wsum[node] + c;
    float4 vp = make_float4(fmaxf(a0.x + a1.x + a2.x + a3.x, 0.f) * wn,
                            fmaxf(a0.y + a1.y + a2.y + a3.y, 0.f) * wn,
                            fmaxf(a0.z + a1.z + a2.z + a3.z, 0.f) * wn,
                            fmaxf(a0.w + a1.w + a2.w + a3.w, 0.f) * wn);

    *reinterpret_cast<float4*>(&sh[wid][lane * 4]) = vp;
    __syncthreads();
    if (wid == 0) {
        float4 s1 = *reinterpret_cast<const float4*>(&sh[1][lane * 4]);
        float4 s2 = *reinterpret_cast<const float4*>(&sh[2][lane * 4]);
        float4 s3 = *reinterpret_cast<const float4*>(&sh[3][lane * 4]);
        float* vp_out = vpart + (size_t)(blockIdx.x & (NVP - 1)) * FH;
        unsafeAtomicAdd(&vp_out[lane * 4 + 0], vp.x + s1.x + s2.x + s3.x);
        unsafeAtomicAdd(&vp_out[lane * 4 + 1], vp.y + s1.y + s2.y + s3.y);
        unsafeAtomicAdd(&vp_out[lane * 4 + 2], vp.z + s1.z + s2.z + s3.z);
        unsafeAtomicAdd(&vp_out[lane * 4 + 3], vp.w + s1.w + s2.w + s3.w);
    }
}

// out = ((v/NN) @ W2 + b2) @ Wh + bh, where v[f] = sum_s vpart[s][f]
__global__ __launch_bounds__(256) void head2_kernel(const float* __restrict__ vpart,
                                                    const float* __restrict__ W2,
                                                    const float* __restrict__ b2,
                                                    const float* __restrict__ Wh,
                                                    const float* __restrict__ bh,
                                                    float* __restrict__ out) {
    __shared__ float vsh[FH];
    __shared__ float m[FH];
    int t = threadIdx.x;
    float vf = 0.0f;
    for (int s = 0; s < NVP; ++s)
        vf += vpart[s * FH + t];
    vsh[t] = vf;
    __syncthreads();
    const float scale = 1.0f / (float)NN;
    float s = 0.0f;
    for (int f = 0; f < FH; ++f)
        s += vsh[f] * W2[f * FH + t];
    m[t] = s * scale + b2[t];
    __syncthreads();
    if (t < FOUT) {
        float o = 0.0f;
        for (int f = 0; f < FH; ++f)
            o += m[f] * Wh[f * FOUT + t];
        out[t] = o + bh[t];
    }
}

// ---------------- launch ----------------

extern "C" void kernel_launch(void* const* d_in, const int* in_sizes, int n_in,
                              void* d_out, int out_size, void* d_ws, size_t ws_size,
                              hipStream_t stream) {
    const float* x   = (const float*)d_in[0];
    const int*   ei  = (const int*)d_in[1];
    const float* W0  = (const float*)d_in[2];
    const float* b0  = (const float*)d_in[3];
    const float* W1  = (const float*)d_in[4];
    const float* b1  = (const float*)d_in[5];
    const float* W2  = (const float*)d_in[6];
    const float* b2  = (const float*)d_in[7];
    const float* Wh  = (const float*)d_in[8];
    const float* bh  = (const float*)d_in[9];
    float* out = (float*)d_out;

    const int* src = ei;        // edge_index[0,:]
    const int* dst = ei + NE;   // edge_index[1,:]

    // workspace layout (16B-aligned blocks)
    float*    inv       = (float*)d_ws;                 // NPAD
    int*      row_start = (int*)(inv + NPAD);           // NPAD (NN+1 used)
    float*    wsum      = (float*)(row_start + NPAD);   // NPAD
    int*      bcnt      = (int*)(wsum + NPAD);          // 256    <- memset with vpart
    float*    vpart     = (float*)(bcnt + 256);         // NVP*256 floats (64 KB)
    int*      bbase     = (int*)(vpart + NVP * FH);     // 320 (257 used)
    int*      bcur      = bbase + 320;                  // 256
    unsigned* inter     = (unsigned*)(bcur + 256);      // NE u32 (3.2 MB)
    float2*   edata     = (float2*)(inter + NE);        // NE float2 (6.4 MB)
    ushort*   W0tH      = (ushort*)(edata + NE);        // [256][128]
    ushort*   W0tL      = W0tH + 256 * 128;
    ushort*   W1tH      = W0tL + 256 * 128;             // [256][256]
    ushort*   xb        = W1tH + 256 * 256;             // [NN2][128] bf16 (12.8 MB)
    ushort*   aggxH     = xb + (size_t)NN2 * 128;       // [NN2][128]
    ushort*   aggxL     = aggxH + (size_t)NN2 * 128;
    ushort*   linb      = aggxH;                        // [NN2][256] bf16 (aggx dead)
    ushort*   h0H       = aggxL + (size_t)NN2 * 128;    // [NN2][256]

    const int gemm_grid = NN2 / 128;                    // 391
    const int nblk_gx = NN2 / 4;
    const int nblk_g  = NN / 4;                         // 12500, exact

    // ---- edge sort + CSR build + prep ----
    hipMemsetAsync(bcnt, 0, (256 + NVP * FH) * sizeof(int), stream);  // bcnt + vpart
    bucket_cnt_kernel<<<NBLK_A, 256, 0, stream>>>(dst, bcnt);
    bucket_scan_kernel<<<1, 256, 0, stream>>>(bcnt, bbase, bcur);
    binA_kernel<<<NBLK_A, 256, 0, stream>>>(src, dst, bcur, inter);
    binB1_kernel<<<NB, 256, 0, stream>>>(inter, bbase, row_start, inv, wsum);
    binB2_kernel<<<NB, 256, 0, stream>>>(inter, bbase, row_start, inv, edata, wsum);
    prep_kernel<<<(NN2 * 32 + 255) / 256, 256, 0, stream>>>(W0, W1, x, W0tH, W0tL, W1tH, xb);

    // layer 0: aggx = agg(xb) [split]; h0 = bf16(relu(aggx @ W0 + b0))   (3-term)
    gather_x_kernel<<<nblk_gx, 256, 0, stream>>>(xb, edata, row_start, inv, aggxH, aggxL);
    gemm_mfma_kernel<3, true><<<gemm_grid, 256, 0, stream>>>(aggxH, aggxL, W0tH, W0tL, b0,
                                                             h0H, FIN);

    // layer 1 GEMM: lin1 = bf16(h0 @ W1)
    gemm_mfma_kernel<1, false><<<gemm_grid, 256, 0, stream>>>(h0H, nullptr, W1tH, nullptr, nullptr,
                                                              linb, FH);

    // fused: layer-1 gather + relu + collapsed layer-2 weighted colsum -> vpart
    gather_colsum_kernel<<<nblk_g, 256, 0, stream>>>(linb, edata, row_start, inv, wsum, b1, vpart);

    // head (reduces vpart internally)
    head2_kernel<<<1, 256, 0, stream>>>(vpart, W2, b2, Wh, bh, out);
}